// Round 7
// baseline (236.752 us; speedup 1.0000x reference)
//
#include <hip/hip_runtime.h>
#include <hip/hip_cooperative_groups.h>
#include <math.h>

namespace cg = cooperative_groups;

#define N_NODES 100000
#define N_EDGES 1600000

#define BK_LOG 7
#define BKW 128                               // nodes per bucket
#define NBK ((N_NODES + BKW - 1) / BKW)       // 782 buckets
#define CAPB 2688   // per-bucket capacity; mean 2046, sigma~45 -> +14 sigma
#define UNS4 3      // int4 load rounds in agg (3*256*4 = 3072 >= CAPB)

#define GS 400                                // scatter chunks
#define EPS (N_EDGES / GS)                    // 4000 edges per chunk (exact)
#define EPS4 (EPS / 4)                        // 1000 int4 per chunk

#define NT_BLOCKS ((N_NODES + 63) / 64)       // 1563 nodeT chunks (64 nodes each)
#define NCHUNK (GS + NT_BLOCKS)               // 1963 phase-A chunks
#define MAXGRID 1024                          // 4 blocks/CU x 256 CUs

// ---------------------------------------------------------------------------
// Single cooperative kernel; all bodies verbatim from the round-1 best
// (127.1 us), re-plumbed as grid-strided phases:
//   phase 0: zero cursors              (replaces hipMemsetAsync dispatch)
//   phase A: 400 scatter chunks + 1563 nodeT chunks (R1's mixed grid),
//            Q/c computed ONCE per block instead of once per nodeT chunk
//   phase B: 782 sortagg buckets       (R1's rank->scan->place->gather)
// Two grid.sync()s replace two kernel-boundary drains + 3 dispatch
// overheads. LDS total ~20 KB -> 4 blocks/CU at launch_bounds(256,4).
// ---------------------------------------------------------------------------
__global__ __launch_bounds__(256, 4) void fused_kernel(
    const float* __restrict__ feat,
    const float* __restrict__ W_in,
    const float* __restrict__ b_in,
    const float* __restrict__ W_edge,
    const float* __restrict__ b_edge,
    const float* __restrict__ W_out,
    const float* __restrict__ b_out,
    const int*   __restrict__ src,
    const int*   __restrict__ dst,
    int* __restrict__ cursor,
    int* __restrict__ ework,
    float4* __restrict__ nodeT,
    float2* __restrict__ out)
{
    cg::grid_group gg = cg::this_grid();
    const int tid = threadIdx.x;
    const int bid = blockIdx.x;
    const int nb  = gridDim.x;

    __shared__ float sP[64 * 4];     // P[m][j]
    __shared__ float sQ[64 * 4];     // Q[k][j], 16B rows
    __shared__ float sc[4];
    __shared__ int   hist[NBK];      // scatter: per-bucket counts
    __shared__ int   base[NBK];      // scatter: global bases
    __shared__ int   ahist[BKW];     // agg: per-node counts
    __shared__ int   abase[BKW];     // agg: per-node bases
    __shared__ int   wtot[2];
    __shared__ int   ssorted[CAPB];  // 10.5 KB

    // ---- phase 0: zero cursors (workspace is poisoned every iteration) ----
    for (int i = bid * 256 + tid; i < NBK; i += nb * 256) cursor[i] = 0;

    // ---- phase A preamble: P, Q, c (once per block) ----
    if (tid < 64) {
        sP[tid * 4 + 0] = W_edge[tid];            // W_u
        sP[tid * 4 + 1] = W_out[tid * 2 + 0];     // W_out[:,0]
        sP[tid * 4 + 2] = W_out[tid * 2 + 1];     // W_out[:,1]
        sP[tid * 4 + 3] = W_edge[64 + tid];       // W_v
    }
    __syncthreads();
    {   // Q[k][j] = sum_m W_in[k][m] * P[m][j]
        const int k = tid >> 2, j = tid & 3;
        float q = 0.f;
        for (int m = 0; m < 64; ++m) q += W_in[k * 64 + m] * sP[m * 4 + j];
        sQ[k * 4 + j] = q;
        if (tid < 4) {
            float cc = 0.f;
            for (int m = 0; m < 64; ++m) cc += b_in[m] * sP[m * 4 + tid];
            sc[tid] = cc;
        }
    }
    __syncthreads();

    gg.sync();   // cursors zeroed everywhere before any cursor atomic

    // ---- phase A: grid-strided scatter + nodeT chunks ----
    for (int chunk = bid; chunk < NCHUNK; chunk += nb) {
        if (chunk < GS) {
            // ---------- scatter chunk (R1 body) ----------
            __syncthreads();
            for (int i = tid; i < NBK; i += 256) hist[i] = 0;
            __syncthreads();

            const int4* src4 = (const int4*)src;
            const int4* dst4 = (const int4*)dst;
            const int   b40  = chunk * EPS4;

            int bb[16], rr[16], pk[16];
            #pragma unroll
            for (int j = 0; j < 4; ++j) {
                const int o4 = j * 256 + tid;
                if (o4 < EPS4) {
                    const int4 d4 = dst4[b40 + o4];
                    const int4 s4 = src4[b40 + o4];
                    const int dv[4] = {d4.x, d4.y, d4.z, d4.w};
                    const int sv[4] = {s4.x, s4.y, s4.z, s4.w};
                    #pragma unroll
                    for (int u = 0; u < 4; ++u) {
                        const int idx = j * 4 + u;
                        const int d = dv[u];
                        const int b = d >> BK_LOG;
                        bb[idx] = b;
                        rr[idx] = atomicAdd(&hist[b], 1);
                        pk[idx] = ((d & (BKW - 1)) << 17) | sv[u];
                    }
                }
            }
            __syncthreads();

            for (int b = tid; b < NBK; b += 256) {
                const int c = hist[b];
                if (c) base[b] = atomicAdd(&cursor[b], c);  // one global atomic
            }
            __syncthreads();

            #pragma unroll
            for (int j = 0; j < 4; ++j) {
                const int o4 = j * 256 + tid;
                if (o4 < EPS4) {
                    #pragma unroll
                    for (int u = 0; u < 4; ++u) {
                        const int idx = j * 4 + u;
                        ework[bb[idx] * CAPB + base[bb[idx]] + rr[idx]] = pk[idx];
                    }
                }
            }
        } else {
            // ---------- nodeT chunk (R1 body; sQ/sc read-only) ----------
            const int c    = chunk - GS;
            const int lane = tid & 63;
            const int wv   = tid >> 6;
            const int n    = c * 64 + wv * 16 + (lane >> 2);   // 16 nodes/wave
            const int ks   = (lane & 3) << 4;                  // 16 k's/lane

            float p0 = 0.f, p1 = 0.f, p2 = 0.f, p3 = 0.f;
            if (n < N_NODES) {
                const float* fr = feat + (size_t)n * 64 + ks;
                #pragma unroll
                for (int i4 = 0; i4 < 4; ++i4) {
                    const float4 f = *(const float4*)(fr + i4 * 4);
                    const float fv[4] = {f.x, f.y, f.z, f.w};
                    #pragma unroll
                    for (int u = 0; u < 4; ++u) {
                        const float4 q = *(const float4*)&sQ[(ks + i4 * 4 + u) * 4];
                        p0 += fv[u] * q.x;
                        p1 += fv[u] * q.y;
                        p2 += fv[u] * q.z;
                        p3 += fv[u] * q.w;
                    }
                }
            }
            #pragma unroll
            for (int off = 1; off <= 2; off <<= 1) {
                p0 += __shfl_xor(p0, off);
                p1 += __shfl_xor(p1, off);
                p2 += __shfl_xor(p2, off);
                p3 += __shfl_xor(p3, off);
            }
            if (n < N_NODES && (lane & 3) == 0)
                nodeT[n] = make_float4(p0 + sc[0], p1 + sc[1], p2 + sc[2], p3 + sc[3]);
        }
    }

    gg.sync();   // ework + cursor + nodeT globally visible

    // ---- phase B: grid-strided sortagg buckets (R1 body) ----
    for (int b = bid; b < NBK; b += nb) {
        __syncthreads();
        if (tid < BKW) ahist[tid] = 0;
        __syncthreads();

        const int cnt = min(cursor[b], CAPB);
        const int4* ew4 = (const int4*)(ework + b * CAPB);   // 16B-aligned

        // vector load + rank (per-element tail guard)
        int4 vv[UNS4];
        int  rk[UNS4][4];
        #pragma unroll
        for (int j = 0; j < UNS4; ++j) {
            const int o = (j * 256 + tid) * 4;
            if (o < cnt) {
                const int4 v = ew4[j * 256 + tid];
                vv[j] = v;
                const int ve[4] = {v.x, v.y, v.z, v.w};
                #pragma unroll
                for (int u = 0; u < 4; ++u)
                    if (o + u < cnt) rk[j][u] = atomicAdd(&ahist[ve[u] >> 17], 1);
            }
        }
        __syncthreads();

        // exclusive scan over 128 per-node counts: 2-wave shfl scan
        int own = 0, inc = 0;
        if (tid < BKW) { own = ahist[tid]; inc = own; }
        #pragma unroll
        for (int off = 1; off < 64; off <<= 1) {
            const int t = __shfl_up(inc, off);
            if ((tid & 63) >= off) inc += t;
        }
        if (tid < BKW && (tid & 63) == 63) wtot[tid >> 6] = inc;
        __syncthreads();
        if (tid < BKW) abase[tid] = inc - own + ((tid >= 64) ? wtot[0] : 0);
        __syncthreads();

        // place into LDS
        #pragma unroll
        for (int j = 0; j < UNS4; ++j) {
            const int o = (j * 256 + tid) * 4;
            if (o < cnt) {
                const int4 v = vv[j];
                const int ve[4] = {v.x, v.y, v.z, v.w};
                #pragma unroll
                for (int u = 0; u < 4; ++u)
                    if (o + u < cnt)
                        ssorted[abase[ve[u] >> 17] + rk[j][u]] = ve[u] & 0x1FFFF;
            }
        }
        __syncthreads();

        // aggregate: 4 lanes per node, 2 passes of 64 nodes, 2-deep unroll
        const int sub = tid & 3;
        const float be  = b_edge[0];
        const float bo0 = b_out[0];
        const float bo1 = b_out[1];

        #pragma unroll
        for (int pass = 0; pass < 2; ++pass) {
            const int l = pass * 64 + (tid >> 2);
            const int n = b * BKW + l;

            float4 tn = make_float4(0.f, 0.f, 0.f, 0.f);
            if (n < N_NODES) tn = nodeT[n];
            const int   beg = abase[l];
            const int   len = ahist[l];
            const float Bn  = tn.w + be;

            float m0 = 0.f, m1 = 0.f;
            int i = sub;
            for (; i + 4 < len; i += 8) {
                const int s0 = ssorted[beg + i];
                const int s1 = ssorted[beg + i + 4];
                const float4 t0 = nodeT[s0];
                const float4 t1 = nodeT[s1];
                const float w0 = 1.0f / (1.0f + __expf(-(t0.x + Bn)));
                const float w1 = 1.0f / (1.0f + __expf(-(t1.x + Bn)));
                m0 += w0 * t0.y + w1 * t1.y;
                m1 += w0 * t0.z + w1 * t1.z;
            }
            if (i < len) {
                const int s0 = ssorted[beg + i];
                const float4 t0 = nodeT[s0];
                const float w0 = 1.0f / (1.0f + __expf(-(t0.x + Bn)));
                m0 += w0 * t0.y;
                m1 += w0 * t0.z;
            }
            m0 += __shfl_xor(m0, 1);
            m1 += __shfl_xor(m1, 1);
            m0 += __shfl_xor(m0, 2);
            m1 += __shfl_xor(m1, 2);

            if (sub == 0 && n < N_NODES) {
                const float o0 = (len ? m0 : tn.y) + bo0;
                const float o1 = (len ? m1 : tn.z) + bo1;
                out[n] = make_float2(o0, o1);
            }
        }
    }
}

// ---------------------------------------------------------------------------
extern "C" void kernel_launch(void* const* d_in, const int* in_sizes, int n_in,
                              void* d_out, int out_size, void* d_ws, size_t ws_size,
                              hipStream_t stream) {
    const float* feat   = (const float*)d_in[0];
    const int*   src    = (const int*)d_in[1];
    const int*   dst    = (const int*)d_in[2];
    const float* W_in   = (const float*)d_in[3];
    const float* b_in   = (const float*)d_in[4];
    const float* W_edge = (const float*)d_in[5];
    const float* b_edge = (const float*)d_in[6];
    const float* W_out  = (const float*)d_in[7];
    const float* b_out  = (const float*)d_in[8];
    float2* out = (float2*)d_out;

    // workspace layout (16B-aligned blocks first)
    float4* nodeT  = (float4*)d_ws;                 // 1.6 MB
    int*    ework  = (int*)(nodeT + N_NODES);       // NBK*CAPB ints (8.4 MB)
    int*    cursor = ework + NBK * CAPB;            // NBK ints

    static int grid = 0;
    if (grid == 0) {
        int maxB = 0;
        if (hipOccupancyMaxActiveBlocksPerMultiprocessor(
                &maxB, fused_kernel, 256, 0) != hipSuccess || maxB < 1)
            maxB = 4;
        long g = (long)maxB * 256;                  // 256 CUs on MI355X
        if (g > MAXGRID) g = MAXGRID;
        if (g < 256) g = 256;
        grid = (int)g;
    }

    void* args[] = {
        (void*)&feat, (void*)&W_in, (void*)&b_in, (void*)&W_edge,
        (void*)&b_edge, (void*)&W_out, (void*)&b_out, (void*)&src,
        (void*)&dst, (void*)&cursor, (void*)&ework, (void*)&nodeT,
        (void*)&out
    };
    hipLaunchCooperativeKernel((void*)fused_kernel, dim3(grid), dim3(256),
                               args, 0, stream);
}

// Round 8
// 124.358 us; speedup vs baseline: 1.9038x; 1.9038x over previous
//
#include <hip/hip_runtime.h>
#include <math.h>

#define N_NODES 100000
#define N_EDGES 1600000

#define BK_LOG 7
#define BKW 128                               // nodes per bucket
#define NBK ((N_NODES + BKW - 1) / BKW)       // 782 buckets
#define CAPB 2688   // per-bucket capacity; mean 2046, sigma~45 -> +14 sigma
#define UNS4 3      // int4 load rounds in agg (3*256*4 = 3072 >= CAPB)

#define GS 128                                // scatter blocks (grid-first)
#define EPS (N_EDGES / GS)                    // 12500 edges per block (exact)
#define EPS4 (EPS / 4)                        // 3125 int4 per block
#define SROUNDS ((EPS4 + 255) / 256)          // 13 load rounds

#define NT_BLOCKS ((N_NODES + 63) / 64)       // 1563 nodeT blocks (64 nodes each)

// ---------------------------------------------------------------------------
// K1 (mixed grid): blocks [0, GS) scatter edges into fixed-capacity 128-node
// bucket regions. Two-pass (histogram -> ONE global cursor atomic per
// non-empty (block,bucket) -> re-read (L2-hot) + rank + write). GS=128:
// mean run per (block,bucket) = 16 records = one full 64B line per writer
// block -- fixes the partial-line cross-XCD write amplification measured in
// R7 (WRITE_SIZE 27 MB vs 10.8 ideal) -- and only ~100K cursor atomics.
// Blocks [GS, ...) compute nodeT = feat @ Q + c, Q = W_in @ P, c = b_in @ P,
// P = [W_u, W_out[:,0], W_out[:,1], W_v] (hidden layer collapsed).
// Record: ((dst&127)<<17 | src), src < 2^17.
// ---------------------------------------------------------------------------
__global__ __launch_bounds__(256) void prep_kernel(
    const float* __restrict__ feat,
    const float* __restrict__ W_in,
    const float* __restrict__ b_in,
    const float* __restrict__ W_edge,
    const float* __restrict__ W_out,
    const int*   __restrict__ src,
    const int*   __restrict__ dst,
    int* __restrict__ cursor,
    int* __restrict__ ework,
    float4* __restrict__ nodeT)
{
    const int tid = threadIdx.x;

    // ---------------- scatter blocks (two-pass, R3 body) ----------------
    if ((int)blockIdx.x < GS) {
        __shared__ int hist[NBK];    // pass-1 counts
        __shared__ int rhist[NBK];   // pass-2 ranks
        __shared__ int gbase[NBK];   // global base from cursor
        for (int i = tid; i < NBK; i += 256) { hist[i] = 0; rhist[i] = 0; }
        __syncthreads();

        const int4* src4 = (const int4*)src;
        const int4* dst4 = (const int4*)dst;
        const int   b40  = (int)blockIdx.x * EPS4;

        // pass 1: histogram dst buckets
        for (int j = 0; j < SROUNDS; ++j) {
            const int o4 = j * 256 + tid;
            if (o4 < EPS4) {
                const int4 d4 = dst4[b40 + o4];
                atomicAdd(&hist[d4.x >> BK_LOG], 1);
                atomicAdd(&hist[d4.y >> BK_LOG], 1);
                atomicAdd(&hist[d4.z >> BK_LOG], 1);
                atomicAdd(&hist[d4.w >> BK_LOG], 1);
            }
        }
        __syncthreads();

        // one global cursor atomic per non-empty (block,bucket)
        for (int i = tid; i < NBK; i += 256) {
            const int c = hist[i];
            if (c) gbase[i] = atomicAdd(&cursor[i], c);
        }
        __syncthreads();

        // pass 2: re-read (L2-hot), rank, write packed records
        for (int j = 0; j < SROUNDS; ++j) {
            const int o4 = j * 256 + tid;
            if (o4 < EPS4) {
                const int4 d4 = dst4[b40 + o4];
                const int4 s4 = src4[b40 + o4];
                const int dv[4] = {d4.x, d4.y, d4.z, d4.w};
                const int sv[4] = {s4.x, s4.y, s4.z, s4.w};
                #pragma unroll
                for (int u = 0; u < 4; ++u) {
                    const int d = dv[u];
                    const int b = d >> BK_LOG;
                    const int r = atomicAdd(&rhist[b], 1);
                    ework[b * CAPB + gbase[b] + r] =
                        ((d & (BKW - 1)) << 17) | sv[u];
                }
            }
        }
        return;
    }

    // ---------------- nodeT blocks ----------------
    __shared__ float sP[64 * 4];   // P[m][j] row-major
    __shared__ float sQ[64 * 4];   // Q[k][j] row-major, 16B rows
    __shared__ float sc[4];

    if (tid < 64) {
        sP[tid * 4 + 0] = W_edge[tid];            // W_u
        sP[tid * 4 + 1] = W_out[tid * 2 + 0];     // W_out[:,0]
        sP[tid * 4 + 2] = W_out[tid * 2 + 1];     // W_out[:,1]
        sP[tid * 4 + 3] = W_edge[64 + tid];       // W_v
    }
    __syncthreads();

    {   // Q[k][j] = sum_m W_in[k][m] * P[m][j]
        const int k = tid >> 2, j = tid & 3;
        float q = 0.f;
        for (int m = 0; m < 64; ++m) q += W_in[k * 64 + m] * sP[m * 4 + j];
        sQ[k * 4 + j] = q;
        if (tid < 4) {
            float cc = 0.f;
            for (int m = 0; m < 64; ++m) cc += b_in[m] * sP[m * 4 + tid];
            sc[tid] = cc;
        }
    }
    __syncthreads();

    const int lane = tid & 63;
    const int wv   = tid >> 6;
    const int n    = ((int)blockIdx.x - GS) * 64 + wv * 16 + (lane >> 2);
    const int ks   = (lane & 3) << 4;                           // 16 k's/lane

    float p0 = 0.f, p1 = 0.f, p2 = 0.f, p3 = 0.f;
    if (n < N_NODES) {
        const float* fr = feat + (size_t)n * 64 + ks;
        #pragma unroll
        for (int i4 = 0; i4 < 4; ++i4) {
            const float4 f = *(const float4*)(fr + i4 * 4);
            const float fv[4] = {f.x, f.y, f.z, f.w};
            #pragma unroll
            for (int u = 0; u < 4; ++u) {
                const float4 q = *(const float4*)&sQ[(ks + i4 * 4 + u) * 4];
                p0 += fv[u] * q.x;
                p1 += fv[u] * q.y;
                p2 += fv[u] * q.z;
                p3 += fv[u] * q.w;
            }
        }
    }
    #pragma unroll
    for (int off = 1; off <= 2; off <<= 1) {
        p0 += __shfl_xor(p0, off);
        p1 += __shfl_xor(p1, off);
        p2 += __shfl_xor(p2, off);
        p3 += __shfl_xor(p3, off);
    }
    if (n < N_NODES && (lane & 3) == 0)
        nodeT[n] = make_float4(p0 + sc[0], p1 + sc[1], p2 + sc[2], p3 + sc[3]);
}

// ---------------------------------------------------------------------------
// K2: fused fine-sort + aggregation + output (R1 winning body, 256 thr).
// One block per 128-node bucket. int4 loads of the bucket region, LDS rank
// by node, 2-wave shfl scan, place src into LDS ssorted, then 4 lanes per
// node (2 passes of 64 nodes) stream its run: gather nodeT[src] (16B,
// L2-resident, 2-deep unrolled), sigmoid, register-acc, quad shfl-combine,
// write out. No global atomics; writes only the output.
// ---------------------------------------------------------------------------
__global__ __launch_bounds__(256) void sortagg_kernel(
    const int* __restrict__ ework,
    const int* __restrict__ cursor,
    const float4* __restrict__ nodeT,
    const float* __restrict__ b_edge,
    const float* __restrict__ b_out,
    float2* __restrict__ out)
{
    __shared__ int hist[BKW];
    __shared__ int sbase[BKW];
    __shared__ int wtot[2];
    __shared__ int ssorted[CAPB];   // 10.5 KB

    const int b   = blockIdx.x;
    const int tid = threadIdx.x;

    if (tid < BKW) hist[tid] = 0;
    __syncthreads();

    const int cnt = min(cursor[b], CAPB);
    const int4* ew4 = (const int4*)(ework + b * CAPB);   // CAPB*4 % 16 == 0

    // vector load + rank (per-element tail guard)
    int4 vv[UNS4];
    int  rk[UNS4][4];
    #pragma unroll
    for (int j = 0; j < UNS4; ++j) {
        const int o = (j * 256 + tid) * 4;
        if (o < cnt) {
            const int4 v = ew4[j * 256 + tid];
            vv[j] = v;
            const int ve[4] = {v.x, v.y, v.z, v.w};
            #pragma unroll
            for (int u = 0; u < 4; ++u)
                if (o + u < cnt) rk[j][u] = atomicAdd(&hist[ve[u] >> 17], 1);
        }
    }
    __syncthreads();

    // exclusive scan over the 128 per-node counts: 2-wave shfl scan
    int own = 0, inc = 0;
    if (tid < BKW) { own = hist[tid]; inc = own; }
    #pragma unroll
    for (int off = 1; off < 64; off <<= 1) {
        const int t = __shfl_up(inc, off);
        if ((tid & 63) >= off) inc += t;
    }
    if (tid < BKW && (tid & 63) == 63) wtot[tid >> 6] = inc;
    __syncthreads();
    if (tid < BKW) sbase[tid] = inc - own + ((tid >= 64) ? wtot[0] : 0);
    __syncthreads();

    // place into LDS
    #pragma unroll
    for (int j = 0; j < UNS4; ++j) {
        const int o = (j * 256 + tid) * 4;
        if (o < cnt) {
            const int4 v = vv[j];
            const int ve[4] = {v.x, v.y, v.z, v.w};
            #pragma unroll
            for (int u = 0; u < 4; ++u)
                if (o + u < cnt)
                    ssorted[sbase[ve[u] >> 17] + rk[j][u]] = ve[u] & 0x1FFFF;
        }
    }
    __syncthreads();

    // aggregate: 4 lanes per node, 2 passes of 64 nodes, 2-deep gather unroll
    const int sub = tid & 3;
    const float be  = b_edge[0];
    const float bo0 = b_out[0];
    const float bo1 = b_out[1];

    #pragma unroll
    for (int pass = 0; pass < 2; ++pass) {
        const int l = pass * 64 + (tid >> 2);
        const int n = b * BKW + l;

        float4 tn = make_float4(0.f, 0.f, 0.f, 0.f);
        if (n < N_NODES) tn = nodeT[n];
        const int   beg = sbase[l];
        const int   len = hist[l];
        const float Bn  = tn.w + be;

        float m0 = 0.f, m1 = 0.f;
        int i = sub;
        for (; i + 4 < len; i += 8) {
            const int s0 = ssorted[beg + i];
            const int s1 = ssorted[beg + i + 4];
            const float4 t0 = nodeT[s0];
            const float4 t1 = nodeT[s1];
            const float w0 = 1.0f / (1.0f + __expf(-(t0.x + Bn)));
            const float w1 = 1.0f / (1.0f + __expf(-(t1.x + Bn)));
            m0 += w0 * t0.y + w1 * t1.y;
            m1 += w0 * t0.z + w1 * t1.z;
        }
        if (i < len) {
            const int s0 = ssorted[beg + i];
            const float4 t0 = nodeT[s0];
            const float w0 = 1.0f / (1.0f + __expf(-(t0.x + Bn)));
            m0 += w0 * t0.y;
            m1 += w0 * t0.z;
        }
        m0 += __shfl_xor(m0, 1);
        m1 += __shfl_xor(m1, 1);
        m0 += __shfl_xor(m0, 2);
        m1 += __shfl_xor(m1, 2);

        if (sub == 0 && n < N_NODES) {
            const float o0 = (len ? m0 : tn.y) + bo0;
            const float o1 = (len ? m1 : tn.z) + bo1;
            out[n] = make_float2(o0, o1);
        }
    }
}

// ---------------------------------------------------------------------------
extern "C" void kernel_launch(void* const* d_in, const int* in_sizes, int n_in,
                              void* d_out, int out_size, void* d_ws, size_t ws_size,
                              hipStream_t stream) {
    const float* feat   = (const float*)d_in[0];
    const int*   src    = (const int*)d_in[1];
    const int*   dst    = (const int*)d_in[2];
    const float* W_in   = (const float*)d_in[3];
    const float* b_in   = (const float*)d_in[4];
    const float* W_edge = (const float*)d_in[5];
    const float* b_edge = (const float*)d_in[6];
    const float* W_out  = (const float*)d_in[7];
    const float* b_out  = (const float*)d_in[8];
    float2* out = (float2*)d_out;

    // workspace layout (16B-aligned blocks first)
    float4* nodeT  = (float4*)d_ws;                 // 1.6 MB
    int*    ework  = (int*)(nodeT + N_NODES);       // NBK*CAPB ints (8.4 MB)
    int*    cursor = ework + NBK * CAPB;            // NBK ints

    hipMemsetAsync(cursor, 0, NBK * sizeof(int), stream);

    prep_kernel<<<GS + NT_BLOCKS, 256, 0, stream>>>(
        feat, W_in, b_in, W_edge, W_out, src, dst, cursor, ework, nodeT);
    sortagg_kernel<<<NBK, 256, 0, stream>>>(
        ework, cursor, nodeT, b_edge, b_out, out);
}

// Round 9
// 120.923 us; speedup vs baseline: 1.9579x; 1.0284x over previous
//
#include <hip/hip_runtime.h>
#include <math.h>

#define N_NODES 100000
#define N_EDGES 1600000

#define BK_LOG 7
#define BKW 128                               // nodes per bucket
#define NBK ((N_NODES + BKW - 1) / BKW)       // 782 buckets
#define CAPB 2688   // per-bucket capacity; mean 2046, sigma~45 -> +14 sigma
#define UNS4 3      // int4 load rounds in agg (3*256*4 = 3072 >= CAPB)

#define GS 128                                // scatter blocks (grid-first)
#define EPS (N_EDGES / GS)                    // 12500 edges per block (exact)
#define EPS4 (EPS / 4)                        // 3125 int4 per block
#define PBT 1024                              // prep block threads
#define SROUNDS ((EPS4 + PBT - 1) / PBT)      // 4 load rounds per pass

#define NODES_PB 256                          // nodes per nodeT block (16 waves)
#define NT_BLOCKS ((N_NODES + NODES_PB - 1) / NODES_PB)   // 391

// ---------------------------------------------------------------------------
// K1 (mixed grid, 1024-thread blocks): blocks [0, GS) scatter edges into
// fixed-capacity 128-node-bucket regions. Two-pass (histogram -> ONE global
// cursor atomic per non-empty (block,bucket) -> re-read (L2-hot) + rank +
// write). GS=128 keeps mean runs at 16 records = one full 64B line per
// writer block (R8-verified: fixes cross-XCD partial-line amplification).
// 1024 threads/block: 16 waves interleave the load->LDS-atomic latency
// chain, rounds drop 26 -> 8 (R8 had 4 waves grinding 26 serial rounds on
// half-idle CUs after nodeT drained).
// Blocks [GS, ...) compute nodeT = feat @ Q + c (256 nodes/block), Q=W_in@P,
// c=b_in@P, P=[W_u, W_out[:,0], W_out[:,1], W_v] (hidden layer collapsed).
// Record: ((dst&127)<<17 | src), src < 2^17.
// ---------------------------------------------------------------------------
__global__ __launch_bounds__(PBT, 4) void prep_kernel(
    const float* __restrict__ feat,
    const float* __restrict__ W_in,
    const float* __restrict__ b_in,
    const float* __restrict__ W_edge,
    const float* __restrict__ W_out,
    const int*   __restrict__ src,
    const int*   __restrict__ dst,
    int* __restrict__ cursor,
    int* __restrict__ ework,
    float4* __restrict__ nodeT)
{
    const int tid = threadIdx.x;

    // ---------------- scatter blocks (two-pass, R8 body @ 1024 thr) -------
    if ((int)blockIdx.x < GS) {
        __shared__ int hist[NBK];    // pass-1 counts
        __shared__ int rhist[NBK];   // pass-2 ranks
        __shared__ int gbase[NBK];   // global base from cursor
        for (int i = tid; i < NBK; i += PBT) { hist[i] = 0; rhist[i] = 0; }
        __syncthreads();

        const int4* src4 = (const int4*)src;
        const int4* dst4 = (const int4*)dst;
        const int   b40  = (int)blockIdx.x * EPS4;

        // pass 1: histogram dst buckets
        #pragma unroll
        for (int j = 0; j < SROUNDS; ++j) {
            const int o4 = j * PBT + tid;
            if (o4 < EPS4) {
                const int4 d4 = dst4[b40 + o4];
                atomicAdd(&hist[d4.x >> BK_LOG], 1);
                atomicAdd(&hist[d4.y >> BK_LOG], 1);
                atomicAdd(&hist[d4.z >> BK_LOG], 1);
                atomicAdd(&hist[d4.w >> BK_LOG], 1);
            }
        }
        __syncthreads();

        // one global cursor atomic per non-empty (block,bucket)
        for (int i = tid; i < NBK; i += PBT) {
            const int c = hist[i];
            if (c) gbase[i] = atomicAdd(&cursor[i], c);
        }
        __syncthreads();

        // pass 2: re-read (L2-hot), rank, write packed records
        #pragma unroll
        for (int j = 0; j < SROUNDS; ++j) {
            const int o4 = j * PBT + tid;
            if (o4 < EPS4) {
                const int4 d4 = dst4[b40 + o4];
                const int4 s4 = src4[b40 + o4];
                const int dv[4] = {d4.x, d4.y, d4.z, d4.w};
                const int sv[4] = {s4.x, s4.y, s4.z, s4.w};
                #pragma unroll
                for (int u = 0; u < 4; ++u) {
                    const int d = dv[u];
                    const int b = d >> BK_LOG;
                    const int r = atomicAdd(&rhist[b], 1);
                    ework[b * CAPB + gbase[b] + r] =
                        ((d & (BKW - 1)) << 17) | sv[u];
                }
            }
        }
        return;
    }

    // ---------------- nodeT blocks (256 nodes, 16 waves) ----------------
    __shared__ float sP[64 * 4];   // P[m][j] row-major
    __shared__ float sQ[64 * 4];   // Q[k][j] row-major, 16B rows
    __shared__ float sc[4];

    if (tid < 64) {
        sP[tid * 4 + 0] = W_edge[tid];            // W_u
        sP[tid * 4 + 1] = W_out[tid * 2 + 0];     // W_out[:,0]
        sP[tid * 4 + 2] = W_out[tid * 2 + 1];     // W_out[:,1]
        sP[tid * 4 + 3] = W_edge[64 + tid];       // W_v
    }
    __syncthreads();

    if (tid < 256) {   // Q[k][j] = sum_m W_in[k][m] * P[m][j]
        const int k = tid >> 2, j = tid & 3;
        float q = 0.f;
        for (int m = 0; m < 64; ++m) q += W_in[k * 64 + m] * sP[m * 4 + j];
        sQ[k * 4 + j] = q;
        if (tid < 4) {
            float cc = 0.f;
            for (int m = 0; m < 64; ++m) cc += b_in[m] * sP[m * 4 + tid];
            sc[tid] = cc;
        }
    }
    __syncthreads();

    const int lane = tid & 63;
    const int wv   = tid >> 6;                                  // 16 waves
    const int n    = ((int)blockIdx.x - GS) * NODES_PB + wv * 16 + (lane >> 2);
    const int ks   = (lane & 3) << 4;                           // 16 k's/lane

    float p0 = 0.f, p1 = 0.f, p2 = 0.f, p3 = 0.f;
    if (n < N_NODES) {
        const float* fr = feat + (size_t)n * 64 + ks;
        #pragma unroll
        for (int i4 = 0; i4 < 4; ++i4) {
            const float4 f = *(const float4*)(fr + i4 * 4);
            const float fv[4] = {f.x, f.y, f.z, f.w};
            #pragma unroll
            for (int u = 0; u < 4; ++u) {
                const float4 q = *(const float4*)&sQ[(ks + i4 * 4 + u) * 4];
                p0 += fv[u] * q.x;
                p1 += fv[u] * q.y;
                p2 += fv[u] * q.z;
                p3 += fv[u] * q.w;
            }
        }
    }
    #pragma unroll
    for (int off = 1; off <= 2; off <<= 1) {
        p0 += __shfl_xor(p0, off);
        p1 += __shfl_xor(p1, off);
        p2 += __shfl_xor(p2, off);
        p3 += __shfl_xor(p3, off);
    }
    if (n < N_NODES && (lane & 3) == 0)
        nodeT[n] = make_float4(p0 + sc[0], p1 + sc[1], p2 + sc[2], p3 + sc[3]);
}

// ---------------------------------------------------------------------------
// K2: fused fine-sort + aggregation + output (R1/R8 winning body, 256 thr).
// One block per 128-node bucket. int4 loads of the bucket region, LDS rank
// by node, 2-wave shfl scan, place src into LDS ssorted, then 4 lanes per
// node (2 passes of 64 nodes) stream its run: gather nodeT[src] (16B,
// L2-resident, 2-deep unrolled), sigmoid, register-acc, quad shfl-combine,
// write out. No global atomics; writes only the output.
// ---------------------------------------------------------------------------
__global__ __launch_bounds__(256) void sortagg_kernel(
    const int* __restrict__ ework,
    const int* __restrict__ cursor,
    const float4* __restrict__ nodeT,
    const float* __restrict__ b_edge,
    const float* __restrict__ b_out,
    float2* __restrict__ out)
{
    __shared__ int hist[BKW];
    __shared__ int sbase[BKW];
    __shared__ int wtot[2];
    __shared__ int ssorted[CAPB];   // 10.5 KB

    const int b   = blockIdx.x;
    const int tid = threadIdx.x;

    if (tid < BKW) hist[tid] = 0;
    __syncthreads();

    const int cnt = min(cursor[b], CAPB);
    const int4* ew4 = (const int4*)(ework + b * CAPB);   // CAPB*4 % 16 == 0

    // vector load + rank (per-element tail guard)
    int4 vv[UNS4];
    int  rk[UNS4][4];
    #pragma unroll
    for (int j = 0; j < UNS4; ++j) {
        const int o = (j * 256 + tid) * 4;
        if (o < cnt) {
            const int4 v = ew4[j * 256 + tid];
            vv[j] = v;
            const int ve[4] = {v.x, v.y, v.z, v.w};
            #pragma unroll
            for (int u = 0; u < 4; ++u)
                if (o + u < cnt) rk[j][u] = atomicAdd(&hist[ve[u] >> 17], 1);
        }
    }
    __syncthreads();

    // exclusive scan over the 128 per-node counts: 2-wave shfl scan
    int own = 0, inc = 0;
    if (tid < BKW) { own = hist[tid]; inc = own; }
    #pragma unroll
    for (int off = 1; off < 64; off <<= 1) {
        const int t = __shfl_up(inc, off);
        if ((tid & 63) >= off) inc += t;
    }
    if (tid < BKW && (tid & 63) == 63) wtot[tid >> 6] = inc;
    __syncthreads();
    if (tid < BKW) sbase[tid] = inc - own + ((tid >= 64) ? wtot[0] : 0);
    __syncthreads();

    // place into LDS
    #pragma unroll
    for (int j = 0; j < UNS4; ++j) {
        const int o = (j * 256 + tid) * 4;
        if (o < cnt) {
            const int4 v = vv[j];
            const int ve[4] = {v.x, v.y, v.z, v.w};
            #pragma unroll
            for (int u = 0; u < 4; ++u)
                if (o + u < cnt)
                    ssorted[sbase[ve[u] >> 17] + rk[j][u]] = ve[u] & 0x1FFFF;
        }
    }
    __syncthreads();

    // aggregate: 4 lanes per node, 2 passes of 64 nodes, 2-deep gather unroll
    const int sub = tid & 3;
    const float be  = b_edge[0];
    const float bo0 = b_out[0];
    const float bo1 = b_out[1];

    #pragma unroll
    for (int pass = 0; pass < 2; ++pass) {
        const int l = pass * 64 + (tid >> 2);
        const int n = b * BKW + l;

        float4 tn = make_float4(0.f, 0.f, 0.f, 0.f);
        if (n < N_NODES) tn = nodeT[n];
        const int   beg = sbase[l];
        const int   len = hist[l];
        const float Bn  = tn.w + be;

        float m0 = 0.f, m1 = 0.f;
        int i = sub;
        for (; i + 4 < len; i += 8) {
            const int s0 = ssorted[beg + i];
            const int s1 = ssorted[beg + i + 4];
            const float4 t0 = nodeT[s0];
            const float4 t1 = nodeT[s1];
            const float w0 = 1.0f / (1.0f + __expf(-(t0.x + Bn)));
            const float w1 = 1.0f / (1.0f + __expf(-(t1.x + Bn)));
            m0 += w0 * t0.y + w1 * t1.y;
            m1 += w0 * t0.z + w1 * t1.z;
        }
        if (i < len) {
            const int s0 = ssorted[beg + i];
            const float4 t0 = nodeT[s0];
            const float w0 = 1.0f / (1.0f + __expf(-(t0.x + Bn)));
            m0 += w0 * t0.y;
            m1 += w0 * t0.z;
        }
        m0 += __shfl_xor(m0, 1);
        m1 += __shfl_xor(m1, 1);
        m0 += __shfl_xor(m0, 2);
        m1 += __shfl_xor(m1, 2);

        if (sub == 0 && n < N_NODES) {
            const float o0 = (len ? m0 : tn.y) + bo0;
            const float o1 = (len ? m1 : tn.z) + bo1;
            out[n] = make_float2(o0, o1);
        }
    }
}

// ---------------------------------------------------------------------------
extern "C" void kernel_launch(void* const* d_in, const int* in_sizes, int n_in,
                              void* d_out, int out_size, void* d_ws, size_t ws_size,
                              hipStream_t stream) {
    const float* feat   = (const float*)d_in[0];
    const int*   src    = (const int*)d_in[1];
    const int*   dst    = (const int*)d_in[2];
    const float* W_in   = (const float*)d_in[3];
    const float* b_in   = (const float*)d_in[4];
    const float* W_edge = (const float*)d_in[5];
    const float* b_edge = (const float*)d_in[6];
    const float* W_out  = (const float*)d_in[7];
    const float* b_out  = (const float*)d_in[8];
    float2* out = (float2*)d_out;

    // workspace layout (16B-aligned blocks first)
    float4* nodeT  = (float4*)d_ws;                 // 1.6 MB
    int*    ework  = (int*)(nodeT + N_NODES);       // NBK*CAPB ints (8.4 MB)
    int*    cursor = ework + NBK * CAPB;            // NBK ints

    hipMemsetAsync(cursor, 0, NBK * sizeof(int), stream);

    prep_kernel<<<GS + NT_BLOCKS, PBT, 0, stream>>>(
        feat, W_in, b_in, W_edge, W_out, src, dst, cursor, ework, nodeT);
    sortagg_kernel<<<NBK, 256, 0, stream>>>(
        ework, cursor, nodeT, b_edge, b_out, out);
}